// Round 7
// baseline (150.731 us; speedup 1.0000x reference)
//
#include <hip/hip_runtime.h>
#include <hip/hip_bf16.h>

#define B_DIM 2048
#define S_DIM 32768
#define G_DIM 4096
#define E_DIM 1024

typedef __bf16 bf16x8 __attribute__((ext_vector_type(8)));
typedef __bf16 bf16x4 __attribute__((ext_vector_type(4)));
typedef float f32x4 __attribute__((ext_vector_type(4)));

__device__ __forceinline__ unsigned short f2bf(float f) {
  unsigned int u = __builtin_bit_cast(unsigned int, f);
  u += 0x7FFFu + ((u >> 16) & 1u);   // round-to-nearest-even (no NaN inputs here)
  return (unsigned short)(u >> 16);
}

__device__ __forceinline__ void async16(void* lds, const void* g) {
  __builtin_amdgcn_global_load_lds(
      (const __attribute__((address_space(1))) unsigned int*)g,
      (__attribute__((address_space(3))) unsigned int*)lds, 16, 0, 0);
}

// Non-returning LDS float atomic add (ds_add_f32). Invisible to the
// compiler's waitcnt model: must be drained with an explicit
// s_waitcnt lgkmcnt(0) before any barrier that readers wait on.
__device__ __forceinline__ void lds_add(float* p, float v) {
  unsigned off = (unsigned)(size_t)(__attribute__((address_space(3))) float*)p;
  asm volatile("ds_add_f32 %0, %1" :: "v"(off), "v"(v));
}

// ---------------- setup A: per-element packed meta --------------------------
// meta1[s] = perm[s] (15b) | orflag (bit15) | bf16(cm) (bits16-31)
__global__ __launch_bounds__(256) void setup_meta(
    const float* __restrict__ w_elem, const int* __restrict__ perm,
    const int* __restrict__ segid, const int* __restrict__ agg,
    unsigned* __restrict__ meta1) {
  int s = blockIdx.x * 256 + threadIdx.x;
  if (s >= S_DIM) return;
  int g = segid[s];
  int a = agg[g];
  float cm = (a == 0) ? 1.0f : (a == 2 ? w_elem[s] : 0.0f);
  meta1[s] = (unsigned)perm[s] | (a == 1 ? 0x8000u : 0u) |
             ((unsigned)f2bf(cm) << 16);
}

// ---------------- setup B: per-32-window run-head mask + first group -------
__global__ __launch_bounds__(256) void setup_runs(
    const int* __restrict__ segid, unsigned* __restrict__ metaH,
    unsigned short* __restrict__ metaG) {
  int t = blockIdx.x * 256 + threadIdx.x;
  if (t >= S_DIM / 32) return;
  int s0 = t * 32;
  int prev = (s0 == 0) ? -1 : segid[s0 - 1];
  unsigned m = 0;
#pragma unroll
  for (int c = 0; c < 8; ++c) {
    int4 gw = *reinterpret_cast<const int4*>(segid + s0 + c * 4);
    if (gw.x != prev) m |= 1u << (c * 4 + 0);
    if (gw.y != gw.x) m |= 1u << (c * 4 + 1);
    if (gw.z != gw.y) m |= 1u << (c * 4 + 2);
    if (gw.w != gw.z) m |= 1u << (c * 4 + 3);
    prev = gw.w;
  }
  metaH[t] = m;
  metaG[t] = (unsigned short)segid[s0];
}

// ---------------- W (f32, [E][G]) -> bf16 ----------------
__global__ __launch_bounds__(256) void conv_w(const float* __restrict__ W,
                                              unsigned short* __restrict__ Wb) {
  size_t i = ((size_t)blockIdx.x * 256 + threadIdx.x) * 4;
  float4 v = *reinterpret_cast<const float4*>(W + i);
  ushort4 o;
  o.x = f2bf(v.x);
  o.y = f2bf(v.y);
  o.z = f2bf(v.z);
  o.w = f2bf(v.w);
  *reinterpret_cast<ushort4*>(Wb + i) = o;
}

// ---------------- stage 1: TWO rows per block, bit-packed gather -----------
// rows b0=2*blk, b1=b0+1 packed per column: xrow2[c] = bf16(x[b0][c]) |
// bf16(x[b1][c])<<16.  One ds_read_b32 gather serves both rows; one meta1
// stream serves both rows; one flush site flushes both rows (interleaved
// acc2[2g]=row0, acc2[2g+1]=row1: interior run = single ds_write_b64,
// boundary = 2x ds_add_f32).  LDS = 128K + 32K = 160 KiB, 1 block/CU.
__global__ __launch_bounds__(1024, 4) void seg_reduce(
    const float* __restrict__ x, const unsigned* __restrict__ meta1,
    const unsigned* __restrict__ metaH, const unsigned short* __restrict__ metaG,
    const int* __restrict__ agg, unsigned short* __restrict__ y) {
  __shared__ unsigned xrow2[S_DIM];   // 128 KB (2 rows bf16-packed)
  __shared__ float acc2[2 * G_DIM];   // 32 KB (interleaved row0/row1)
  const int t = threadIdx.x;
  const int b0 = blockIdx.x * 2;

#pragma unroll
  for (int i = 0; i < (2 * G_DIM) / (1024 * 4); ++i)
    *reinterpret_cast<float4*>(&acc2[(i * 1024 + t) * 4]) =
        make_float4(0.f, 0.f, 0.f, 0.f);

  // stage both rows: 2 coalesced float4 loads -> packed cvt -> 16B ds_write
  const float4* xg0 = reinterpret_cast<const float4*>(x + (size_t)b0 * S_DIM);
  const float4* xg1 =
      reinterpret_cast<const float4*>(x + (size_t)(b0 + 1) * S_DIM);
#pragma unroll
  for (int i = 0; i < S_DIM / 4 / 1024; ++i) {
    float4 v0 = xg0[i * 1024 + t];
    float4 v1 = xg1[i * 1024 + t];
    uint4 p;
    p.x = (unsigned)__builtin_bit_cast(unsigned short, (__bf16)v0.x) |
          ((unsigned)__builtin_bit_cast(unsigned short, (__bf16)v1.x) << 16);
    p.y = (unsigned)__builtin_bit_cast(unsigned short, (__bf16)v0.y) |
          ((unsigned)__builtin_bit_cast(unsigned short, (__bf16)v1.y) << 16);
    p.z = (unsigned)__builtin_bit_cast(unsigned short, (__bf16)v0.z) |
          ((unsigned)__builtin_bit_cast(unsigned short, (__bf16)v1.z) << 16);
    p.w = (unsigned)__builtin_bit_cast(unsigned short, (__bf16)v0.w) |
          ((unsigned)__builtin_bit_cast(unsigned short, (__bf16)v1.w) << 16);
    *reinterpret_cast<uint4*>(&xrow2[(i * 1024 + t) * 4]) = p;
  }
  __syncthreads();

  const int s0 = t * 32;
  const unsigned mrun = metaH[t];
  const bool firstPlain = (mrun & 1u) != 0;  // first run starts at s0
  int g = metaG[t];
  float sum0 = 0.0f, sum1 = 0.0f;
  int nflush = 0;

  for (int h = 0; h < 2; ++h) {  // two halves of 16 elems
    const int sb = s0 + h * 16;
    uint4 ma = *reinterpret_cast<const uint4*>(meta1 + sb);
    uint4 mb = *reinterpret_cast<const uint4*>(meta1 + sb + 4);
    uint4 mc = *reinterpret_cast<const uint4*>(meta1 + sb + 8);
    uint4 md = *reinterpret_cast<const uint4*>(meta1 + sb + 12);
    unsigned m[16] = {ma.x, ma.y, ma.z, ma.w, mb.x, mb.y, mb.z, mb.w,
                      mc.x, mc.y, mc.z, mc.w, md.x, md.y, md.z, md.w};
    unsigned xu[16];
#pragma unroll
    for (int j = 0; j < 16; ++j) xu[j] = xrow2[m[j] & 0x7FFF];
    const unsigned mh = mrun >> (h * 16);
#pragma unroll
    for (int j = 0; j < 16; ++j) {
      if (h + j > 0 && (mh & (1u << j))) {  // run head: flush previous run
        if (nflush == 0 && !firstPlain) {
          lds_add(&acc2[2 * g], sum0);  // first run extends into prev thread
          lds_add(&acc2[2 * g + 1], sum1);
        } else {
          *reinterpret_cast<float2*>(&acc2[2 * g]) =
              make_float2(sum0, sum1);  // exclusively-owned run
        }
        ++nflush;
        sum0 = 0.0f;
        sum1 = 0.0f;
        ++g;
      }
      float x0 = __builtin_bit_cast(float, xu[j] << 16);
      float x1 = __builtin_bit_cast(float, xu[j] & 0xFFFF0000u);
      float cm = __builtin_bit_cast(float, m[j] & 0xFFFF0000u);
      if (m[j] & 0x8000u) {
        sum0 += (xu[j] & 0xFFFFu) ? 1.0f : 0.0f;
        sum1 += (xu[j] >> 16) ? 1.0f : 0.0f;
      } else {
        sum0 += x0 * cm;
        sum1 += x1 * cm;
      }
    }
  }
  lds_add(&acc2[2 * g], sum0);  // last run may extend into next thread
  lds_add(&acc2[2 * g + 1], sum1);

  // Drain asm ds_adds (invisible to compiler waitcnt model) before barrier.
  asm volatile("s_waitcnt lgkmcnt(0)" ::: "memory");
  __syncthreads();

#pragma unroll
  for (int i = 0; i < G_DIM / 1024; ++i) {
    int g2 = t + i * 1024;
    float2 vv = *reinterpret_cast<const float2*>(&acc2[2 * g2]);
    float v0 = vv.x, v1 = vv.y;
    if (agg[g2] == 1) {  // acc holds nnz count
      v0 = (v0 > 0.0f) ? 1.0f : 0.0f;
      v1 = (v1 > 0.0f) ? 1.0f : 0.0f;
    }
    v0 = fmaxf(v0, 0.0f);  // relu
    v1 = fmaxf(v1, 0.0f);
    y[(size_t)b0 * G_DIM + g2] = f2bf(v0);
    y[(size_t)(b0 + 1) * G_DIM + g2] = f2bf(v1);
  }
}

// ---------------- stage 2: out[b,e] = sum_g yr[b,g] * W[e,g]  (bf16 MFMA) --
__global__ __launch_bounds__(256) void gemm_bt(
    const unsigned short* __restrict__ A,   // y bf16 [B_DIM][G_DIM]
    const unsigned short* __restrict__ Bw,  // W bf16 [E_DIM][G_DIM]
    float* __restrict__ C) {                // out f32 [B_DIM][E_DIM]
  __shared__ __align__(16) unsigned short As[64 * 64];  // 8 KB
  __shared__ __align__(16) unsigned short Bs[64 * 64];  // 8 KB
  const int t = threadIdx.x;
  const int lane = t & 63;
  const int wid = t >> 6;
  const int wr = wid >> 1;  // wave row (M)
  const int wc = wid & 1;   // wave col (N)
  const int row0 = blockIdx.y * 64;
  const int col0 = blockIdx.x * 64;

  // staging: thread t covers LDS byte t*16 -> (row=t>>3, slot=t&7)
  const int r_ = t >> 3;  // 0..31
  const int s_ = t & 7;
  const int ksw = (s_ ^ (r_ & 7)) * 8;  // inverse-swizzled k offset (elements)
  const unsigned short* Ag0 = A + (size_t)(row0 + r_) * G_DIM + ksw;
  const unsigned short* Ag1 = A + (size_t)(row0 + r_ + 32) * G_DIM + ksw;
  const unsigned short* Bg0 = Bw + (size_t)(col0 + r_) * G_DIM + ksw;
  const unsigned short* Bg1 = Bw + (size_t)(col0 + r_ + 32) * G_DIM + ksw;

  char* AsB = (char*)As;
  char* BsB = (char*)Bs;
  char* dA0 = AsB + wid * 1024;          // wave-uniform LDS dst bases
  char* dA1 = AsB + 4096 + wid * 1024;
  char* dB0 = BsB + wid * 1024;
  char* dB1 = BsB + 4096 + wid * 1024;

  const int lm = lane & 15;
  const int lk = lane >> 4;  // 0..3

  f32x4 acc[2][2] = {};

  for (int kt = 0; kt < G_DIM; kt += 64) {
    async16(dA0, Ag0 + kt);
    async16(dA1, Ag1 + kt);
    async16(dB0, Bg0 + kt);
    async16(dB1, Bg1 + kt);
    __syncthreads();  // drains vmcnt before barrier
#pragma unroll
    for (int kk = 0; kk < 2; ++kk) {
      bf16x8 af[2], bfr[2];
#pragma unroll
      for (int m = 0; m < 2; ++m) {
        int row = wr * 32 + m * 16 + lm;
        int slot = (kk * 4 + lk) ^ (row & 7);
        af[m] = *(const bf16x8*)(AsB + row * 128 + slot * 16);
      }
#pragma unroll
      for (int n = 0; n < 2; ++n) {
        int row = wc * 32 + n * 16 + lm;
        int slot = (kk * 4 + lk) ^ (row & 7);
        bfr[n] = *(const bf16x8*)(BsB + row * 128 + slot * 16);
      }
#pragma unroll
      for (int m = 0; m < 2; ++m)
#pragma unroll
        for (int n = 0; n < 2; ++n)
          acc[m][n] = __builtin_amdgcn_mfma_f32_16x16x32_bf16(af[m], bfr[n],
                                                              acc[m][n], 0, 0, 0);
    }
    __syncthreads();  // protect LDS before next stage
  }

  // C/D layout: col = lane&15, row = (lane>>4)*4 + reg
#pragma unroll
  for (int m = 0; m < 2; ++m) {
    int r = row0 + wr * 32 + m * 16 + lk * 4;
#pragma unroll
    for (int n = 0; n < 2; ++n) {
      int c = col0 + wc * 32 + n * 16 + lm;
#pragma unroll
      for (int q = 0; q < 4; ++q) {
        C[(size_t)(r + q) * E_DIM + c] = acc[m][n][q];
      }
    }
  }
}

extern "C" void kernel_launch(void* const* d_in, const int* in_sizes, int n_in,
                              void* d_out, int out_size, void* d_ws, size_t ws_size,
                              hipStream_t stream) {
  const float* x = (const float*)d_in[0];
  const float* W = (const float*)d_in[1];
  const float* w_elem = (const float*)d_in[2];
  const int* perm = (const int*)d_in[3];
  const int* segid = (const int*)d_in[4];
  const int* agg = (const int*)d_in[5];
  float* out = (float*)d_out;

  char* ws = (char*)d_ws;
  unsigned short* y = (unsigned short*)ws;  // B*G bf16 = 16 MB
  unsigned short* Wb =
      (unsigned short*)(ws + (size_t)B_DIM * G_DIM * 2);  // E*G bf16 = 8 MB
  unsigned* meta1 =
      (unsigned*)(ws + (size_t)B_DIM * G_DIM * 2 + (size_t)E_DIM * G_DIM * 2);
  unsigned* metaH = (unsigned*)((char*)meta1 + (size_t)S_DIM * 4);
  unsigned short* metaG = (unsigned short*)((char*)metaH + (S_DIM / 32) * 4);

  hipLaunchKernelGGL(setup_meta, dim3(S_DIM / 256), dim3(256), 0, stream,
                     w_elem, perm, segid, agg, meta1);
  hipLaunchKernelGGL(setup_runs, dim3((S_DIM / 32) / 256), dim3(256), 0,
                     stream, segid, metaH, metaG);
  hipLaunchKernelGGL(conv_w, dim3((E_DIM * G_DIM / 4) / 256), dim3(256), 0,
                     stream, W, Wb);
  hipLaunchKernelGGL(seg_reduce, dim3(B_DIM / 2), dim3(1024), 0, stream, x,
                     meta1, metaH, metaG, agg, y);
  hipLaunchKernelGGL(gemm_bt, dim3(E_DIM / 64, B_DIM / 64), dim3(256), 0,
                     stream, y, Wb, out);
}